// Round 1
// baseline (653.282 us; speedup 1.0000x reference)
//
#include <hip/hip_runtime.h>
#include <math.h>

#define HMAP 160
#define WMAP 160
#define CIN 1024
#define NCOL 392
#define NPIX 25600
#define NROI 300
#define NALL 600

// output flat offsets (floats)
#define OUT_CLS      0
#define OUT_CLSRES   1200
#define OUT_CLSSCORE 1800
#define OUT_MASK     2400
#define OUT_ROISALL  237600
#define OUT_BBOX     240600
#define OUT_KEEP     243000

// ---------------------------------------------------------------------------
// GEMM: C[25600,392] = feat[25600,1024] @ [W_ps | W_bb] + [b_ps | b_bb]
// fp32, BM=128 BN=64 BK=16, 256 threads, 8x4 micro-tile.
// grid: x = n-block (0..6)  [fastest-varying -> consecutive blocks share A tile],
//       y = m-block (0..199)
// ---------------------------------------------------------------------------
__global__ __launch_bounds__(256) void gemm_maps(
    const float* __restrict__ A,
    const float* __restrict__ Wps, const float* __restrict__ bps,
    const float* __restrict__ Wbb, const float* __restrict__ bbb,
    float* __restrict__ C)
{
    __shared__ __align__(16) float As[16][132];  // [k][row], +4 pad
    __shared__ __align__(16) float Bs[16][64];   // [k][col]
    const int t  = threadIdx.x;
    const int bn = blockIdx.x;   // 0..6
    const int bm = blockIdx.y;   // 0..199
    const int tx = t & 15;       // col group (4 cols)
    const int ty = t >> 4;       // row group (8 rows)

    // A staging: thread -> (row = t/4, kq = (t%4)*4), two rows (arow, arow+64)
    const int arow = t >> 2;
    const int akq  = (t & 3) << 2;
    const float* Ap = A + (size_t)(bm * 128 + arow) * CIN + akq;

    // B staging: thread -> (k = t/16, 4 cols at (t%16)*4)
    const int bk = t >> 4;
    const int bc = (t & 15) << 2;
    const int colbase = bn * 64 + bc;

    float acc[8][4];
#pragma unroll
    for (int i = 0; i < 8; i++)
#pragma unroll
        for (int j = 0; j < 4; j++) acc[i][j] = 0.f;

    for (int k0 = 0; k0 < CIN; k0 += 16) {
        float4 a0 = *(const float4*)(Ap + k0);
        float4 a1 = *(const float4*)(Ap + 64 * CIN + k0);
        float bv[4];
        const int krow = k0 + bk;
#pragma unroll
        for (int i = 0; i < 4; i++) {
            int col = colbase + i;
            bv[i] = (col < 196) ? Wps[krow * 196 + col]
                  : (col < 392) ? Wbb[krow * 196 + col - 196] : 0.f;
        }
        __syncthreads();
        As[akq + 0][arow] = a0.x; As[akq + 1][arow] = a0.y;
        As[akq + 2][arow] = a0.z; As[akq + 3][arow] = a0.w;
        As[akq + 0][arow + 64] = a1.x; As[akq + 1][arow + 64] = a1.y;
        As[akq + 2][arow + 64] = a1.z; As[akq + 3][arow + 64] = a1.w;
        *(float4*)&Bs[bk][bc] = make_float4(bv[0], bv[1], bv[2], bv[3]);
        __syncthreads();
#pragma unroll
        for (int kk = 0; kk < 16; kk++) {
            float4 b  = *(float4*)&Bs[kk][tx << 2];
            float4 x0 = *(float4*)&As[kk][ty << 3];
            float4 x1 = *(float4*)&As[kk][(ty << 3) + 4];
            float av[8] = {x0.x, x0.y, x0.z, x0.w, x1.x, x1.y, x1.z, x1.w};
            float bw[4] = {b.x, b.y, b.z, b.w};
#pragma unroll
            for (int i = 0; i < 8; i++)
#pragma unroll
                for (int j = 0; j < 4; j++)
                    acc[i][j] = fmaf(av[i], bw[j], acc[i][j]);
        }
    }

    // epilogue: add bias, store (mask cols >= 392)
    const int col0 = bn * 64 + (tx << 2);
    float bias[4];
#pragma unroll
    for (int j = 0; j < 4; j++) {
        int col = col0 + j;
        bias[j] = (col < 196) ? bps[col] : (col < 392) ? bbb[col - 196] : 0.f;
    }
#pragma unroll
    for (int i = 0; i < 8; i++) {
        int row = bm * 128 + (ty << 3) + i;
        float* Cp = C + (size_t)row * NCOL + col0;
        if (col0 + 3 < NCOL) {
            float4 v = make_float4(acc[i][0] + bias[0], acc[i][1] + bias[1],
                                   acc[i][2] + bias[2], acc[i][3] + bias[3]);
            *(float4*)Cp = v;
        } else {
#pragma unroll
            for (int j = 0; j < 4; j++)
                if (col0 + j < NCOL) Cp[j] = acc[i][j] + bias[j];
        }
    }
}

// ---------------------------------------------------------------------------
// bilinear sample setup, matching reference exactly
// ---------------------------------------------------------------------------
__device__ __forceinline__ void bil_setup(
    float r1, float r2, float r3, float r4, int h, int w,
    int& o00, int& o01, int& o10, int& o11,
    float& w00, float& w01, float& w10, float& w11, int& ij)
{
    float x1 = r1 * 0.125f, y1 = r2 * 0.125f;
    float x2 = r3 * 0.125f, y2 = r4 * 0.125f;
    float bw = (x2 - x1) / 7.0f;
    float bh = (y2 - y1) / 7.0f;
    int i = h >> 1, sy = h & 1, j = w >> 1, sx = w & 1;
    float yy = y1 + ((float)i + ((float)sy + 0.5f) * 0.5f) * bh;
    float xx = x1 + ((float)j + ((float)sx + 0.5f) * 0.5f) * bw;
    float y0f = floorf(yy), x0f = floorf(xx);
    float wy = yy - y0f, wx = xx - x0f;
    int iy0 = min(max((int)y0f, 0), HMAP - 1);
    int iy1 = min(iy0 + 1, HMAP - 1);
    int ix0 = min(max((int)x0f, 0), WMAP - 1);
    int ix1 = min(ix0 + 1, WMAP - 1);
    o00 = (iy0 * WMAP + ix0) * NCOL;
    o01 = (iy0 * WMAP + ix1) * NCOL;
    o10 = (iy1 * WMAP + ix0) * NCOL;
    o11 = (iy1 * WMAP + ix1) * NCOL;
    w00 = (1.f - wy) * (1.f - wx);
    w01 = (1.f - wy) * wx;
    w10 = wy * (1.f - wx);
    w11 = wy * wx;
    ij = i * 7 + j;
}

// ---------------------------------------------------------------------------
// part2_2 over original rois -> offsets -> proposals -> rois_all; bbox[0:300]
// ---------------------------------------------------------------------------
__global__ __launch_bounds__(256) void k_offsets_proposals(
    const float* __restrict__ maps, const float* __restrict__ rois,
    float* __restrict__ ws_roisall, float* __restrict__ out)
{
    const int r = blockIdx.x, t = threadIdx.x;
    __shared__ float4 red[256];
    const float* roi = rois + r * 5;
    const float r0 = roi[0], r1 = roi[1], r2 = roi[2], r3 = roi[3], r4 = roi[4];
    float4 v = make_float4(0.f, 0.f, 0.f, 0.f);
    if (t < 196) {
        int h = t / 14, w = t % 14;
        int o00, o01, o10, o11, ij;
        float w00, w01, w10, w11;
        bil_setup(r1, r2, r3, r4, h, w, o00, o01, o10, o11, w00, w01, w10, w11, ij);
        float vals[4];
#pragma unroll
        for (int a = 0; a < 4; a++) {
            int c = 196 + a * 49 + ij;  // bb part of maps
            vals[a] = maps[o00 + c] * w00 + maps[o01 + c] * w01 +
                      maps[o10 + c] * w10 + maps[o11 + c] * w11;
        }
        v = make_float4(vals[0], vals[1], vals[2], vals[3]);
    }
    red[t] = v;
    __syncthreads();
    for (int s = 128; s > 0; s >>= 1) {
        if (t < s) {
            red[t].x += red[t + s].x; red[t].y += red[t + s].y;
            red[t].z += red[t + s].z; red[t].w += red[t + s].w;
        }
        __syncthreads();
    }
    if (t == 0) {
        float dx = red[0].x / 196.f, dy = red[0].y / 196.f;
        float dw = red[0].z / 196.f, dh = red[0].w / 196.f;
        out[OUT_BBOX + r * 4 + 0] = dx;
        out[OUT_BBOX + r * 4 + 1] = dy;
        out[OUT_BBOX + r * 4 + 2] = dw;
        out[OUT_BBOX + r * 4 + 3] = dh;
        // bbox_transform_inv on (r1,r2,r3,r4)
        float w_ = r3 - r1 + 1.f, h_ = r4 - r2 + 1.f;
        float cx = r1 + 0.5f * w_, cy = r2 + 0.5f * h_;
        float pcx = dx * w_ + cx, pcy = dy * h_ + cy;
        float pw = expf(dw) * w_, ph = expf(dh) * h_;
        float px1 = fminf(fmaxf(pcx - 0.5f * pw, 0.f), 1279.f);
        float py1 = fminf(fmaxf(pcy - 0.5f * ph, 0.f), 1279.f);
        float px2 = fminf(fmaxf(pcx + 0.5f * pw, 0.f), 1279.f);
        float py2 = fminf(fmaxf(pcy + 0.5f * ph, 0.f), 1279.f);
        // rois_all row r (copy) and row 300+r (proposal), to ws and out
        float rowA[5] = {r0, r1, r2, r3, r4};
        float rowB[5] = {0.f, px1, py1, px2, py2};
#pragma unroll
        for (int c = 0; c < 5; c++) {
            ws_roisall[r * 5 + c] = rowA[c];
            ws_roisall[(NROI + r) * 5 + c] = rowB[c];
            out[OUT_ROISALL + r * 5 + c] = rowA[c];
            out[OUT_ROISALL + (NROI + r) * 5 + c] = rowB[c];
        }
    }
}

// ---------------------------------------------------------------------------
// part2_2 over proposals -> bbox[300:600]
// ---------------------------------------------------------------------------
__global__ __launch_bounds__(256) void k_bbox_props(
    const float* __restrict__ maps, const float* __restrict__ ws_roisall,
    float* __restrict__ out)
{
    const int r = blockIdx.x, t = threadIdx.x;   // proposal index 0..299
    __shared__ float4 red[256];
    const float* roi = ws_roisall + (NROI + r) * 5;
    const float r1 = roi[1], r2 = roi[2], r3 = roi[3], r4 = roi[4];
    float4 v = make_float4(0.f, 0.f, 0.f, 0.f);
    if (t < 196) {
        int h = t / 14, w = t % 14;
        int o00, o01, o10, o11, ij;
        float w00, w01, w10, w11;
        bil_setup(r1, r2, r3, r4, h, w, o00, o01, o10, o11, w00, w01, w10, w11, ij);
        float vals[4];
#pragma unroll
        for (int a = 0; a < 4; a++) {
            int c = 196 + a * 49 + ij;
            vals[a] = maps[o00 + c] * w00 + maps[o01 + c] * w01 +
                      maps[o10 + c] * w10 + maps[o11 + c] * w11;
        }
        v = make_float4(vals[0], vals[1], vals[2], vals[3]);
    }
    red[t] = v;
    __syncthreads();
    for (int s = 128; s > 0; s >>= 1) {
        if (t < s) {
            red[t].x += red[t + s].x; red[t].y += red[t + s].y;
            red[t].z += red[t + s].z; red[t].w += red[t + s].w;
        }
        __syncthreads();
    }
    if (t == 0) {
        out[OUT_BBOX + (NROI + r) * 4 + 0] = red[0].x / 196.f;
        out[OUT_BBOX + (NROI + r) * 4 + 1] = red[0].y / 196.f;
        out[OUT_BBOX + (NROI + r) * 4 + 2] = red[0].z / 196.f;
        out[OUT_BBOX + (NROI + r) * 4 + 3] = red[0].w / 196.f;
    }
}

// ---------------------------------------------------------------------------
// part2_1 over all 600 rois -> cls, cls_result, cls_score, mask_result
// ---------------------------------------------------------------------------
__global__ __launch_bounds__(256) void k_cls_mask(
    const float* __restrict__ maps, const float* __restrict__ ws_roisall,
    float* __restrict__ scores_ws, float* __restrict__ out)
{
    const int r = blockIdx.x, t = threadIdx.x;
    __shared__ float4 vbuf[196];
    __shared__ float2 red[256];
    __shared__ int s_cr;
    const float* roi = ws_roisall + r * 5;
    const float r1 = roi[1], r2 = roi[2], r3 = roi[3], r4 = roi[4];
    float2 cm = make_float2(0.f, 0.f);
    if (t < 196) {
        int h = t / 14, w = t % 14;
        int o00, o01, o10, o11, ij;
        float w00, w01, w10, w11;
        bil_setup(r1, r2, r3, r4, h, w, o00, o01, o10, o11, w00, w01, w10, w11, ij);
        float vals[4];
#pragma unroll
        for (int a = 0; a < 4; a++) {
            int c = a * 49 + ij;  // ps part of maps
            vals[a] = maps[o00 + c] * w00 + maps[o01 + c] * w01 +
                      maps[o10 + c] * w10 + maps[o11 + c] * w11;
        }
        vbuf[t] = make_float4(vals[0], vals[1], vals[2], vals[3]);
        // cls_max[q] = max_p v[2p+q]
        cm.x = fmaxf(vals[0], vals[2]);
        cm.y = fmaxf(vals[1], vals[3]);
    }
    red[t] = cm;
    __syncthreads();
    for (int s = 128; s > 0; s >>= 1) {
        if (t < s) { red[t].x += red[t + s].x; red[t].y += red[t + s].y; }
        __syncthreads();
    }
    if (t == 0) {
        float a0 = red[0].x / 196.f, a1 = red[0].y / 196.f;
        float m = fmaxf(a0, a1);
        float e0 = expf(a0 - m), e1 = expf(a1 - m);
        float inv = 1.f / (e0 + e1);
        float c0 = e0 * inv, c1 = e1 * inv;
        int cr = (a1 > a0) ? 1 : 0;
        float cs = fmaxf(c0, c1);
        out[OUT_CLS + r * 2 + 0] = c0;
        out[OUT_CLS + r * 2 + 1] = c1;
        out[OUT_CLSRES + r] = (float)cr;
        out[OUT_CLSSCORE + r] = cs;
        scores_ws[r] = cs;
        s_cr = cr;
    }
    __syncthreads();
    if (t < 196) {
        int cr = s_cr;
        float4 vv = vbuf[t];
        float v0 = cr ? vv.y : vv.x;   // v[cr]     (p=0)
        float v1 = cr ? vv.w : vv.z;   // v[2+cr]   (p=1)
        float m = fmaxf(v0, v1);
        float e0 = expf(v0 - m), e1 = expf(v1 - m);
        float inv = 1.f / (e0 + e1);
        out[OUT_MASK + r * 392 + t * 2 + 0] = e0 * inv;
        out[OUT_MASK + r * 392 + t * 2 + 1] = e1 * inv;
    }
}

// ---------------------------------------------------------------------------
// NMS stage 1: stable descending rank-sort of scores; emit order + sorted boxes
// ---------------------------------------------------------------------------
__global__ __launch_bounds__(640) void k_sort(
    const float* __restrict__ scores_ws, const float* __restrict__ ws_roisall,
    int* __restrict__ order, float* __restrict__ sbox)
{
    __shared__ float ls[NALL];
    __shared__ float lb[NALL][4];
    const int t = threadIdx.x;
    if (t < NALL) {
        ls[t] = scores_ws[t];
        lb[t][0] = ws_roisall[t * 5 + 1];
        lb[t][1] = ws_roisall[t * 5 + 2];
        lb[t][2] = ws_roisall[t * 5 + 3];
        lb[t][3] = ws_roisall[t * 5 + 4];
    }
    __syncthreads();
    if (t < NALL) {
        float s = ls[t];
        int rank = 0;
        for (int j = 0; j < NALL; j++) {
            float sj = ls[j];
            rank += (sj > s) || (sj == s && j < t);
        }
        order[rank] = t;
        float x1 = lb[t][0], y1 = lb[t][1], x2 = lb[t][2], y2 = lb[t][3];
        sbox[rank]            = x1;
        sbox[NALL + rank]     = y1;
        sbox[2 * NALL + rank] = x2;
        sbox[3 * NALL + rank] = y2;
        sbox[4 * NALL + rank] = fmaxf(x2 - x1, 0.f) * fmaxf(y2 - y1, 0.f);
    }
}

// ---------------------------------------------------------------------------
// NMS stage 2: per sorted box i, 600-bit (iou>thr) mask as 10 uint64 words
// ---------------------------------------------------------------------------
__global__ __launch_bounds__(640) void k_iou_mask(
    const float* __restrict__ sbox, unsigned long long* __restrict__ mask)
{
    const int i = blockIdx.x, t = threadIdx.x;
    const float ix1 = sbox[i], iy1 = sbox[NALL + i];
    const float ix2 = sbox[2 * NALL + i], iy2 = sbox[3 * NALL + i];
    const float ia = sbox[4 * NALL + i];
    bool pred = false;
    if (t < NALL) {
        float jx1 = sbox[t], jy1 = sbox[NALL + t];
        float jx2 = sbox[2 * NALL + t], jy2 = sbox[3 * NALL + t];
        float ja = sbox[4 * NALL + t];
        float xx1 = fmaxf(ix1, jx1), yy1 = fmaxf(iy1, jy1);
        float xx2 = fminf(ix2, jx2), yy2 = fminf(iy2, jy2);
        float inter = fmaxf(xx2 - xx1, 0.f) * fmaxf(yy2 - yy1, 0.f);
        float iou = inter / (ia + ja - inter + 1e-8f);
        pred = iou > 0.3f;
    }
    unsigned long long b = __ballot(pred ? 1 : 0);
    if ((t & 63) == 0) mask[(size_t)i * 10 + (t >> 6)] = b;
}

// ---------------------------------------------------------------------------
// NMS stage 3: single-wave greedy suppression + emit keep[300]
// ---------------------------------------------------------------------------
__global__ __launch_bounds__(64) void k_greedy(
    const unsigned long long* __restrict__ mask, const int* __restrict__ order,
    float* __restrict__ out)
{
    const int l = threadIdx.x;
    unsigned long long keepw = 0ull;
    unsigned long long cur = (l < 10) ? mask[l] : 0ull;
    for (int i = 0; i < NALL; i++) {
        unsigned long long nxt =
            (l < 10 && i + 1 < NALL) ? mask[(size_t)(i + 1) * 10 + l] : 0ull;
        bool sup = __any((cur & keepw) != 0ull);
        if (!sup && l == (i >> 6)) keepw |= 1ull << (i & 63);
        cur = nxt;
    }
    __shared__ unsigned long long kw[10];
    if (l < 10) kw[l] = keepw;
    __syncthreads();
    int total = 0;
    for (int w = 0; w < 10; w++) total += __popcll(kw[w]);
    for (int tt = l; tt < 300; tt += 64) {
        float o = -1.f;
        if (tt < total) {
            int rem = tt, s = 0;
            for (int w = 0; w < 10; w++) {
                int pc = __popcll(kw[w]);
                if (rem >= pc) { rem -= pc; continue; }
                unsigned long long word = kw[w];
                while (rem--) word &= word - 1;
                s = w * 64 + (__ffsll((long long)word) - 1);
                break;
            }
            o = (float)order[s];
        }
        out[OUT_KEEP + tt] = o;
    }
}

// ---------------------------------------------------------------------------
extern "C" void kernel_launch(void* const* d_in, const int* in_sizes, int n_in,
                              void* d_out, int out_size, void* d_ws, size_t ws_size,
                              hipStream_t stream)
{
    const float* feat = (const float*)d_in[0];
    const float* Wps  = (const float*)d_in[1];
    const float* bps  = (const float*)d_in[2];
    const float* Wbb  = (const float*)d_in[3];
    const float* bbb  = (const float*)d_in[4];
    const float* rois = (const float*)d_in[5];
    float* out = (float*)d_out;

    // workspace layout (floats)
    float* maps       = (float*)d_ws;            // 25600*392 = 10,035,200
    float* ws_roisall = maps + (size_t)NPIX * NCOL;  // 3000
    float* scores     = ws_roisall + NALL * 5;       // 600
    int*   order      = (int*)(scores + NALL);       // 600
    float* sbox       = (float*)(order + NALL);      // 3000
    unsigned long long* mask = (unsigned long long*)(sbox + 5 * NALL); // 6000 u64

    hipLaunchKernelGGL(gemm_maps, dim3(7, 200), dim3(256), 0, stream,
                       feat, Wps, bps, Wbb, bbb, maps);
    hipLaunchKernelGGL(k_offsets_proposals, dim3(NROI), dim3(256), 0, stream,
                       maps, rois, ws_roisall, out);
    hipLaunchKernelGGL(k_bbox_props, dim3(NROI), dim3(256), 0, stream,
                       maps, ws_roisall, out);
    hipLaunchKernelGGL(k_cls_mask, dim3(NALL), dim3(256), 0, stream,
                       maps, ws_roisall, scores, out);
    hipLaunchKernelGGL(k_sort, dim3(1), dim3(640), 0, stream,
                       scores, ws_roisall, order, sbox);
    hipLaunchKernelGGL(k_iou_mask, dim3(NALL), dim3(640), 0, stream,
                       sbox, mask);
    hipLaunchKernelGGL(k_greedy, dim3(1), dim3(64), 0, stream,
                       mask, order, out);
}